// Round 12
// baseline (431.319 us; speedup 1.0000x reference)
//
#include <hip/hip_runtime.h>
#include <hip/hip_bf16.h>
#include <math.h>

#define NN 10000
#define NE 131072

typedef __attribute__((ext_vector_type(8))) short short8;
typedef __attribute__((ext_vector_type(4))) float f32x4;

__device__ __forceinline__ float silu_f(float x) {
    return x / (1.0f + __expf(-x));
}

// round-to-nearest-even f32 -> bf16 (finite inputs only)
__device__ __forceinline__ unsigned short f2bf(float f) {
    unsigned int u = __float_as_uint(f);
    u += 0x7FFFu + ((u >> 16) & 1u);
    return (unsigned short)(u >> 16);
}

// packed pair via HW v_cvt_pk_bf16_f32 (x = low half)
__device__ __forceinline__ unsigned int pk_bf16(float lo, float hi) {
    __hip_bfloat162 h = __float22bfloat162_rn(float2{lo, hi});
    return *reinterpret_cast<unsigned int*>(&h);
}

// ---------------------------------------------------------------------------
// D1: prep (692 blocks).  hist already zeroed by D0 memset.  (R7-proven)
// ---------------------------------------------------------------------------
__global__ __launch_bounds__(256)
void prep_kernel(const int* __restrict__ A,
                 const int* __restrict__ edst,
                 const float* __restrict__ emb_tab,
                 const float* __restrict__ W1, const float* __restrict__ b1,
                 const float* __restrict__ W2, const float* __restrict__ b2,
                 const float* __restrict__ W3, const float* __restrict__ b3,
                 const float* __restrict__ fcW1,
                 const float* __restrict__ fcW2,
                 const float* __restrict__ fcW3,
                 const float* __restrict__ fcW4,
                 int* __restrict__ hist,
                 int* __restrict__ rank,
                 float* __restrict__ outg,
                 float* __restrict__ Ai,
                 unsigned short* __restrict__ Wg,
                 unsigned short* __restrict__ Bg)
{
    const int blk = blockIdx.x;
    const int tid = threadIdx.x;

    if (blk < 40) {
        // node MLP -> Ai
        int nd = blk * 256 + tid;
        if (nd >= NN) return;
        int a = A[nd];
        float h[16];
#pragma unroll
        for (int i = 0; i < 16; ++i) h[i] = emb_tab[a * 16 + i];
        float h1[64];
#pragma unroll
        for (int j = 0; j < 64; ++j) h1[j] = b1[j];
#pragma unroll
        for (int i = 0; i < 16; ++i) {
            float hv = h[i];
#pragma unroll
            for (int j = 0; j < 64; ++j) h1[j] += hv * W1[i * 64 + j];
        }
#pragma unroll
        for (int j = 0; j < 64; ++j) h1[j] = silu_f(h1[j]);
        float h2[32];
#pragma unroll
        for (int j = 0; j < 32; ++j) h2[j] = b2[j];
#pragma unroll
        for (int i = 0; i < 64; ++i) {
            float hv = h1[i];
#pragma unroll
            for (int j = 0; j < 32; ++j) h2[j] += hv * W2[i * 32 + j];
        }
#pragma unroll
        for (int j = 0; j < 32; ++j) h2[j] = silu_f(h2[j]);
#pragma unroll
        for (int j = 0; j < 8; ++j) {
            float s = b3[j];
#pragma unroll
            for (int i = 0; i < 32; ++i) s += h2[i] * W3[i * 8 + j];
            Ai[nd * 8 + j] = s;
        }
    } else if (blk < 80) {
        // prep_W: 20 frags of 512 bf16
        int i = (blk - 40) * 256 + tid;   // [0, 10240)
        int j    = i & 7;
        int lane = (i >> 3) & 63;
        int f    = i >> 9;
        int q = lane >> 4, n = lane & 15;
        int L, kf, nt;
        if (f < 4)       { L = 1; kf = 0;             nt = f; }
        else if (f < 12) { L = 2; kf = (f - 4) >> 2;  nt = (f - 4) & 3; }
        else             { L = 3; kf = (f - 12) >> 2; nt = (f - 12) & 3; }
        int k = kf * 32 + q * 8 + j;
        int col = nt * 16 + n;
        float v = 0.0f;
        if (L == 1)      { if (k < 10) v = fcW1[k * 64 + col]; }
        else if (L == 2) v = fcW2[k * 64 + col];
        else             v = fcW3[k * 64 + col];
        Wg[i] = f2bf(v);
    } else if (blk < 592) {
        // prep_B inverse-mapped + histogram/rank
        int linear = (blk - 80) * 256 + tid;   // [0, 131072)
        rank[linear] = atomicAdd(&hist[edst[linear]], 1);
        if (linear < 114688) {                 // 64 * 1792 real elements
            int k = linear / 1792;
            int t = linear - k * 1792;
            int uv, wc;
            if (t < 1024)      { uv = t >> 4;            wc = t & 15; }
            else if (t < 1536) { int r = t - 1024; uv = r >> 3; wc = 16 + (r & 7); }
            else               { int r = t - 1536; uv = r >> 2; wc = 24 + (r & 3); }
            int h  = uv >> 5;
            int q  = (uv >> 3) & 3;
            int j  = uv & 7;
            int nt = wc >> 4;
            int n  = wc & 15;
            int i  = (k << 11) | (h << 10) | (nt << 9) | (((q << 4) | n) << 3) | j;
            Bg[i] = f2bf(fcW4[linear]);
        } else {                               // zero padding: wc in [28,32)
            int z  = linear - 114688;          // [0, 16384)
            int k  = z >> 8;
            int r  = z & 255;
            int uv = r >> 2;
            int c2 = z & 3;
            int h  = uv >> 5;
            int q  = (uv >> 3) & 3;
            int j  = uv & 7;
            int i  = (k << 11) | (h << 10) | (1 << 9) | (((q << 4) | (12 + c2)) << 3) | j;
            Bg[i] = 0;
        }
    } else {
        // zero out
        int t = (blk - 592) * 256 + tid;
        float4 z = float4{0.f, 0.f, 0.f, 0.f};
        for (int r = t; r < 150000; r += 25600)
            ((float4*)outg)[r] = z;
    }
}

// ---------------------------------------------------------------------------
// D2: scan+scatter (512 blocks), atomic-free.  (R7-proven)
// ---------------------------------------------------------------------------
__global__ __launch_bounds__(256)
void scanrank_kernel(const int* __restrict__ edst,
                     const int* __restrict__ hist,
                     const int* __restrict__ rank,
                     int* __restrict__ sortidx)
{
    __shared__ int offs[NN];    // 40000 B
    __shared__ int part[256];
    const int tid = threadIdx.x;

    int loc[40];
    int s = 0;
    if (tid < 250) {
        const int4* h4 = (const int4*)(hist) + tid * 10;
#pragma unroll
        for (int v = 0; v < 10; ++v) {
            int4 x = h4[v];
            loc[v * 4 + 0] = x.x; loc[v * 4 + 1] = x.y;
            loc[v * 4 + 2] = x.z; loc[v * 4 + 3] = x.w;
            s += x.x + x.y + x.z + x.w;
        }
    } else {
#pragma unroll
        for (int r = 0; r < 40; ++r) loc[r] = 0;
    }
    part[tid] = s;
    __syncthreads();
#pragma unroll
    for (int off = 1; off < 256; off <<= 1) {
        int v = (tid >= off) ? part[tid - off] : 0;
        __syncthreads();
        part[tid] += v;
        __syncthreads();
    }
    if (tid < 250) {
        int run = part[tid] - s;
        int base = tid * 40;
#pragma unroll
        for (int r = 0; r < 40; ++r) { offs[base + r] = run; run += loc[r]; }
    }
    __syncthreads();

    int e = blockIdx.x * 256 + tid;
    int d = edst[e];
    sortidx[offs[d] + rank[e]] = e;
}

// ---------------------------------------------------------------------------
// D3: fused edge pipeline, K-SPLIT WAVE PAIRS (R11 structure) + RACE FIX.
// R11's failure: the pair's waves are not in lockstep, and layers 1-2 update
// actw IN PLACE -- wave A could overwrite emb/L1 activations before wave B
// had loaded them into registers.  Fix: a block-wide __syncthreads() between
// the register LOADS and the in-place WRITES of layer 1 and layer 2.  After
// the barrier every wave holds the previous layer in registers, so the
// (identical-byte) overwrites are benign.  Layer 3 writes a separate w3T
// buffer with disjoint per-wave rows -> no barrier.  4 barriers total, all
// cheap (no global_load_lds -> trivial vmcnt drains).
// LDS: actb 17408 + w3T 17408 + sdb 512 + shb 4096 = 39424 -> 4 blocks/CU.
// ---------------------------------------------------------------------------
__global__ __launch_bounds__(256, 4)
void edge_fused_kernel(const float* __restrict__ pos,
                       const int* __restrict__ batch,
                       const int* __restrict__ esrc,
                       const int* __restrict__ edst,
                       const float* __restrict__ shifts,
                       const float* __restrict__ cell,
                       const unsigned short* __restrict__ Wg,
                       const unsigned short* __restrict__ Bg,
                       const int* __restrict__ sortidx,
                       const float* __restrict__ Ai,
                       const int* __restrict__ hist,
                       float* __restrict__ out_g)
{
    __shared__ __align__(16) unsigned short actb[2][64 * 68]; // 2 x 8704 B
    __shared__ __align__(16) unsigned short w3Tb[2][64 * 68]; // 2 x 8704 B
    __shared__ int   sdb[128];                                // packed s|(d<<16)
    __shared__ __align__(16) float shb[2][64 * 8];            // per-edge sh

    const int tid  = threadIdx.x;
    const int wave = tid >> 6;
    const int lane = tid & 63;
    const int grp  = wave >> 1;      // edge-group within block (0,1)
    const int kh   = wave & 1;       // k-half owned by this wave
    const int q    = lane >> 4;
    const int n    = lane & 15;
    const int i    = blockIdx.x * 128 + grp * 64 + lane;

    unsigned short* actw = actb[grp];
    unsigned short* w3T  = w3Tb[grp];

    // ---- geometry (1 lane = 1 edge; both waves of the pair do identical
    // work and write identical bytes; each wave writes ALL 64 rows itself) --
    int e = sortidx[i];
    int s = esrc[e], d = edst[e];
    sdb[grp * 64 + lane] = s | (d << 16);
    int b = batch[s];
    const float* C = cell + b * 9;
    float sx = shifts[e * 3 + 0], sy = shifts[e * 3 + 1], sz = shifts[e * 3 + 2];
    float vx = pos[d * 3 + 0] - pos[s * 3 + 0] + sx * C[0] + sy * C[3] + sz * C[6];
    float vy = pos[d * 3 + 1] - pos[s * 3 + 1] + sx * C[1] + sy * C[4] + sz * C[7];
    float vz = pos[d * 3 + 2] - pos[s * 3 + 2] + sx * C[2] + sy * C[5] + sz * C[8];
    float len = sqrtf(vx * vx + vy * vy + vz * vz);
    float inv = 1.0f / fmaxf(len, 1e-9f);
    float ux = vx * inv, uy = vy * inv, uz = vz * inv;
    {
        const float s3c  = 1.7320508075688772f;
        const float s5c  = 2.2360679774997896f;
        const float s15c = 3.872983346207417f;
        float* shw = shb[grp];
        *(float4*)&shw[lane * 8]     = float4{s3c * ux, s3c * uy, s3c * uz,
                                              s15c * ux * uz};
        *(float4*)&shw[lane * 8 + 4] = float4{s15c * ux * uy,
                                              s5c * (uy * uy - 0.5f * (ux * ux + uz * uz)),
                                              s15c * uy * uz,
                                              0.5f * s15c * (uz * uz - ux * ux)};
    }

    // soft_one_hot (sqrt(10) cancels with fc_W1's /sqrt(10))
    float embv[10];
    float base = len * 2.75f;
#pragma unroll
    for (int ii = 0; ii < 10; ++ii) {
        float ddv = base - (float)(ii + 1);
        embv[ii] = __expf(-ddv * ddv) * (1.0f / 1.12f);
    }
    {
        unsigned int u0 = pk_bf16(embv[0], embv[1]);
        unsigned int u1 = pk_bf16(embv[2], embv[3]);
        unsigned int u2 = pk_bf16(embv[4], embv[5]);
        unsigned int u3 = pk_bf16(embv[6], embv[7]);
        unsigned int u4 = pk_bf16(embv[8], embv[9]);
        uint2* arow = (uint2*)&actw[lane * 68];
        arow[0] = uint2{u0, u1};
        arow[1] = uint2{u2, u3};
        arow[2] = uint2{u4, 0u};
        arow[3] = uint2{0u, 0u};
        arow[4] = uint2{0u, 0u};
        arow[5] = uint2{0u, 0u};
        arow[6] = uint2{0u, 0u};
        arow[7] = uint2{0u, 0u};
    }

    union AF { unsigned int u[4]; short8 s8; };
    const f32x4 Z4 = (f32x4){0.f, 0.f, 0.f, 0.f};

    auto loadA = [&](int t, int kf) -> AF {
        const unsigned short* ap = &actw[(t * 16 + n) * 68 + kf * 32 + q * 8];
        uint2 a = *(const uint2*)ap;
        uint2 c = *(const uint2*)(ap + 4);
        AF f; f.u[0] = a.x; f.u[1] = a.y; f.u[2] = c.x; f.u[3] = c.y;
        return f;
    };
    auto loadW = [&](int f) -> short8 {   // direct global (L2-resident)
        return *(const short8*)&Wg[(f * 64 + lane) * 8];
    };

    // ---- layer 1: K=32 (padded emb), N=64 (redundant across pair) ----
    {
        AF A1[4];
#pragma unroll
        for (int t = 0; t < 4; ++t) A1[t] = loadA(t, 0);

        // RACE FIX: all waves must finish reading emb before anyone
        // overwrites actw with layer-1 outputs.
        __syncthreads();

#pragma unroll
        for (int nt = 0; nt < 4; ++nt) {
            short8 W0 = loadW(nt);
            f32x4 Cc[4];
#pragma unroll
            for (int t = 0; t < 4; ++t)
                Cc[t] = __builtin_amdgcn_mfma_f32_16x16x32_bf16(A1[t].s8, W0, Z4, 0, 0, 0);
#pragma unroll
            for (int t = 0; t < 4; ++t)
#pragma unroll
                for (int r = 0; r < 4; ++r)
                    actw[(t * 16 + q * 4 + r) * 68 + nt * 16 + n] = f2bf(silu_f(Cc[t][r]));
        }
    }

    // ---- layer 2: K=64 (redundant across pair) ----
    {
        AF A2[4][2];
#pragma unroll
        for (int t = 0; t < 4; ++t)
#pragma unroll
            for (int kf = 0; kf < 2; ++kf) A2[t][kf] = loadA(t, kf);

        // RACE FIX: all waves must finish reading layer-1 activations
        // before anyone overwrites actw with layer-2 outputs.
        __syncthreads();

#pragma unroll
        for (int nt = 0; nt < 4; ++nt) {
            short8 Wk0 = loadW(4 + nt);
            short8 Wk1 = loadW(8 + nt);
            f32x4 Cc[4];
#pragma unroll
            for (int t = 0; t < 4; ++t) {
                Cc[t] = __builtin_amdgcn_mfma_f32_16x16x32_bf16(A2[t][0].s8, Wk0, Z4, 0, 0, 0);
                Cc[t] = __builtin_amdgcn_mfma_f32_16x16x32_bf16(A2[t][1].s8, Wk1, Cc[t], 0, 0, 0);
            }
#pragma unroll
            for (int t = 0; t < 4; ++t)
#pragma unroll
                for (int r = 0; r < 4; ++r)
                    actw[(t * 16 + q * 4 + r) * 68 + nt * 16 + n] = f2bf(silu_f(Cc[t][r] * 0.125f));
        }
    }

    // ---- layer 3: K=64, nt split by k-half -> w3T rows [32*kh, 32*kh+32).
    // Reads actw (own wave wrote all rows), writes SEPARATE buffer w3T with
    // disjoint per-wave rows -> no barrier needed. ----
    {
        AF A3[4][2];
#pragma unroll
        for (int t = 0; t < 4; ++t)
#pragma unroll
            for (int kf = 0; kf < 2; ++kf) A3[t][kf] = loadA(t, kf);
#pragma unroll
        for (int ntl = 0; ntl < 2; ++ntl) {
            int nt = kh * 2 + ntl;
            short8 Wk0 = loadW(12 + nt);
            short8 Wk1 = loadW(16 + nt);
            f32x4 Cc[4];
#pragma unroll
            for (int t = 0; t < 4; ++t) {
                Cc[t] = __builtin_amdgcn_mfma_f32_16x16x32_bf16(A3[t][0].s8, Wk0, Z4, 0, 0, 0);
                Cc[t] = __builtin_amdgcn_mfma_f32_16x16x32_bf16(A3[t][1].s8, Wk1, Cc[t], 0, 0, 0);
            }
#pragma unroll
            for (int t = 0; t < 4; ++t)
#pragma unroll
                for (int r = 0; r < 4; ++r)
                    w3T[(nt * 16 + n) * 68 + t * 16 + q * 4 + r] = f2bf(silu_f(Cc[t][r] * 0.125f));
        }
    }

    // ---- register double-buffered B stream over this wave's 16 chunks ----
    const unsigned char* BgB = (const unsigned char*)Bg;
    short8 BA[8], BB[8];
    const int cbase = kh * 16;   // chunks [cbase, cbase+16) = k [32kh, 32kh+32)

    auto LOADB = [&](short8 (&Bf)[8], int c) {
#pragma unroll
        for (int f = 0; f < 8; ++f)
            Bf[f] = *(const short8*)(BgB +
                (((size_t)((c * 8 + f) * 64 + lane)) << 4));
    };

    LOADB(BA, cbase);   // latency hides under P-pack below

    // k-invariant P fragments: P[e, uv=h*32+q*8+j] = As[h*4+q]*Ad[j]
    AF P[4][2];
#pragma unroll
    for (int t = 0; t < 4; ++t) {
        int eL = grp * 64 + t * 16 + n;
        int sd = sdb[eL];
        int ss  = sd & 0xFFFF;
        int dd2 = sd >> 16;
        float As0 = Ai[ss * 8 + q];
        float As1 = Ai[ss * 8 + 4 + q];
        float4 d0 = *(const float4*)&Ai[dd2 * 8];
        float4 d1 = *(const float4*)&Ai[dd2 * 8 + 4];
        float Ad[8] = {d0.x, d0.y, d0.z, d0.w, d1.x, d1.y, d1.z, d1.w};
#pragma unroll
        for (int h = 0; h < 2; ++h) {
            float s0 = h ? As1 : As0;
            P[t][h].u[0] = pk_bf16(s0 * Ad[0], s0 * Ad[1]);
            P[t][h].u[1] = pk_bf16(s0 * Ad[2], s0 * Ad[3]);
            P[t][h].u[2] = pk_bf16(s0 * Ad[4], s0 * Ad[5]);
            P[t][h].u[3] = pk_bf16(s0 * Ad[6], s0 * Ad[7]);
        }
    }

    f32x4 out[4][2];
#pragma unroll
    for (int t = 0; t < 4; ++t)
#pragma unroll
        for (int nt = 0; nt < 2; ++nt)
            out[t][nt] = (f32x4){0.f, 0.f, 0.f, 0.f};

    // fragment index f = kk*4 + h*2 + nt  (matches Bg layout)
    auto COMPUTE = [&](short8 (&Bf)[8], int c) {
#pragma unroll
        for (int kk = 0; kk < 2; ++kk) {
            int k = c * 2 + kk;
#pragma unroll
            for (int t = 0; t < 4; ++t) {
                uint2 v = *(const uint2*)&w3T[k * 68 + t * 16 + q * 4];
                float w0 = __uint_as_float(v.x << 16);
                float w1 = __uint_as_float(v.x & 0xFFFF0000u);
                float w2 = __uint_as_float(v.y << 16);
                float w3 = __uint_as_float(v.y & 0xFFFF0000u);
#pragma unroll
                for (int nt = 0; nt < 2; ++nt) {
                    f32x4 Q = __builtin_amdgcn_mfma_f32_16x16x32_bf16(
                        P[t][0].s8, Bf[kk * 4 + nt], Z4, 0, 0, 0);
                    Q = __builtin_amdgcn_mfma_f32_16x16x32_bf16(
                        P[t][1].s8, Bf[kk * 4 + 2 + nt], Q, 0, 0, 0);
                    out[t][nt][0] += w0 * Q[0];
                    out[t][nt][1] += w1 * Q[1];
                    out[t][nt][2] += w2 * Q[2];
                    out[t][nt][3] += w3 * Q[3];
                }
            }
        }
    };

#pragma unroll 1
    for (int cp = 0; cp < 8; ++cp) {
        int c0 = cbase + cp * 2, c1 = c0 + 1;
        LOADB(BB, c1);                  // prefetch odd chunk
        COMPUTE(BA, c0);                // hides BB's latency
        if (cp < 7) LOADB(BA, c0 + 2);  // prefetch next even chunk
        COMPUTE(BB, c1);                // hides BA's latency
    }

    // ---- feat overlay: wave kh=0 -> actb[grp], kh=1 -> w3Tb[grp].
    // Barrier: all actw/w3T reads (layer-3 A3 + B-loop w3) are done. ----
    __syncthreads();

    float* featMine = (float*)(kh == 0 ? actw : w3T);   // [64][33] fp32
#pragma unroll
    for (int t = 0; t < 4; ++t) {
#pragma unroll
        for (int r = 0; r < 4; ++r) {
            int row = t * 16 + q * 4 + r;
            featMine[row * 33 + n]      = out[t][0][r];
            featMine[row * 33 + 16 + n] = out[t][1][r];
        }
    }

    // Barrier: both halves' feats visible to the pair.
    __syncthreads();

    // ---- epilogue: wave kh reduces edges [32kh, 32kh+32) over
    // featA+featB using the precomputed sh table ----
    const float* featA = (const float*)actw;
    const float* featB = (const float*)w3T;

    if (lane < 60) {
        int j = lane;
        int cc, sidx = 0;
        bool is0 = (j < 16);
        if (j < 16)      { cc = j; }
        else if (j < 40) { cc = 16 + (j - 16) / 3; sidx = (j - 16) % 3; }
        else             { cc = 24 + (j - 40) / 5; sidx = 3 + (j - 40) % 5; }

        const float* shw = shb[grp];
        const int e0 = kh * 32;
        int cur_d = sdb[grp * 64 + e0] >> 16;
        float acc = 0.f;
        for (int e2 = e0; e2 < e0 + 32; ++e2) {
            int d_e = sdb[grp * 64 + e2] >> 16;   // wave-uniform
            if (d_e != cur_d) {
                int cnt = hist[cur_d];
                atomicAdd(&out_g[cur_d * 60 + j], acc * (1.0f / 64.0f) / (float)cnt);
                acc = 0.f;
                cur_d = d_e;
            }
            float f  = featA[e2 * 33 + cc] + featB[e2 * 33 + cc];
            float sh = shw[e2 * 8 + sidx];
            if (is0) sh = 1.0f;
            acc += f * sh;
        }
        int cnt = hist[cur_d];
        atomicAdd(&out_g[cur_d * 60 + j], acc * (1.0f / 64.0f) / (float)cnt);
    }
}

extern "C" void kernel_launch(void* const* d_in, const int* in_sizes, int n_in,
                              void* d_out, int out_size, void* d_ws, size_t ws_size,
                              hipStream_t stream)
{
    const float* pos     = (const float*)d_in[0];
    const int*   A       = (const int*)d_in[1];
    const int*   batch   = (const int*)d_in[2];
    const int*   esrc    = (const int*)d_in[3];
    const int*   edst    = (const int*)d_in[4];
    const float* shifts  = (const float*)d_in[5];
    const float* cell    = (const float*)d_in[6];
    const float* emb_tab = (const float*)d_in[7];
    const float* fitW1   = (const float*)d_in[8];
    const float* fitb1   = (const float*)d_in[9];
    const float* fitW2   = (const float*)d_in[10];
    const float* fitb2   = (const float*)d_in[11];
    const float* fitW3   = (const float*)d_in[12];
    const float* fitb3   = (const float*)d_in[13];
    const float* fcW1    = (const float*)d_in[14];
    const float* fcW2    = (const float*)d_in[15];
    const float* fcW3    = (const float*)d_in[16];
    const float* fcW4    = (const float*)d_in[17];

    float* out = (float*)d_out;

    // workspace layout (all 16B-aligned)
    char* W = (char*)d_ws;
    float* Ai      = (float*)W;  W += (size_t)NN * 8 * 4;        // 320000
    int* sortidx   = (int*)W;    W += (size_t)NE * 4;            // 524288
    int* rank      = (int*)W;    W += (size_t)NE * 4;            // 524288
    int* hist      = (int*)W;    W += (size_t)NN * 4;            // 40000
    unsigned short* Bg = (unsigned short*)W; W += (size_t)131072 * 2;
    unsigned short* Wg = (unsigned short*)W; W += (size_t)10240 * 2;

    // D0: zero hist only (rank is fully overwritten by prep)
    hipMemsetAsync(hist, 0, (size_t)NN * 4, stream);

    // D1: prep (MLP, W/B fragment packing, histogram + rank, out zeroing)
    prep_kernel<<<692, 256, 0, stream>>>(
        A, edst, emb_tab, fitW1, fitb1, fitW2, fitb2, fitW3, fitb3,
        fcW1, fcW2, fcW3, fcW4, hist, rank, out, Ai, Wg, Bg);

    // D2: per-block redundant scan + atomic-free scatter
    scanrank_kernel<<<NE / 256, 256, 0, stream>>>(edst, hist, rank, sortidx);

    // D3: fused edge pipeline (k-split wave pairs + race-fix barriers)
    edge_fused_kernel<<<NE / 128, 256, 0, stream>>>(
        pos, batch, esrc, edst, shifts, cell, Wg, Bg,
        sortidx, Ai, hist, out);
}

// Round 13
// 200.502 us; speedup vs baseline: 2.1512x; 2.1512x over previous
//
#include <hip/hip_runtime.h>
#include <hip/hip_bf16.h>
#include <math.h>

#define NN 10000
#define NE 131072

typedef __attribute__((ext_vector_type(8))) short short8;
typedef __attribute__((ext_vector_type(4))) float f32x4;

__device__ __forceinline__ float silu_f(float x) {
    return x / (1.0f + __expf(-x));
}

// round-to-nearest-even f32 -> bf16 (finite inputs only)
__device__ __forceinline__ unsigned short f2bf(float f) {
    unsigned int u = __float_as_uint(f);
    u += 0x7FFFu + ((u >> 16) & 1u);
    return (unsigned short)(u >> 16);
}

// packed pair via HW v_cvt_pk_bf16_f32 (x = low half)
__device__ __forceinline__ unsigned int pk_bf16(float lo, float hi) {
    __hip_bfloat162 h = __float22bfloat162_rn(float2{lo, hi});
    return *reinterpret_cast<unsigned int*>(&h);
}

// ---------------------------------------------------------------------------
// D1: prep (692 blocks).  hist already zeroed by D0 memset.  (R7-proven)
// ---------------------------------------------------------------------------
__global__ __launch_bounds__(256)
void prep_kernel(const int* __restrict__ A,
                 const int* __restrict__ edst,
                 const float* __restrict__ emb_tab,
                 const float* __restrict__ W1, const float* __restrict__ b1,
                 const float* __restrict__ W2, const float* __restrict__ b2,
                 const float* __restrict__ W3, const float* __restrict__ b3,
                 const float* __restrict__ fcW1,
                 const float* __restrict__ fcW2,
                 const float* __restrict__ fcW3,
                 const float* __restrict__ fcW4,
                 int* __restrict__ hist,
                 int* __restrict__ rank,
                 float* __restrict__ outg,
                 float* __restrict__ Ai,
                 unsigned short* __restrict__ Wg,
                 unsigned short* __restrict__ Bg)
{
    const int blk = blockIdx.x;
    const int tid = threadIdx.x;

    if (blk < 40) {
        // node MLP -> Ai
        int nd = blk * 256 + tid;
        if (nd >= NN) return;
        int a = A[nd];
        float h[16];
#pragma unroll
        for (int i = 0; i < 16; ++i) h[i] = emb_tab[a * 16 + i];
        float h1[64];
#pragma unroll
        for (int j = 0; j < 64; ++j) h1[j] = b1[j];
#pragma unroll
        for (int i = 0; i < 16; ++i) {
            float hv = h[i];
#pragma unroll
            for (int j = 0; j < 64; ++j) h1[j] += hv * W1[i * 64 + j];
        }
#pragma unroll
        for (int j = 0; j < 64; ++j) h1[j] = silu_f(h1[j]);
        float h2[32];
#pragma unroll
        for (int j = 0; j < 32; ++j) h2[j] = b2[j];
#pragma unroll
        for (int i = 0; i < 64; ++i) {
            float hv = h1[i];
#pragma unroll
            for (int j = 0; j < 32; ++j) h2[j] += hv * W2[i * 32 + j];
        }
#pragma unroll
        for (int j = 0; j < 32; ++j) h2[j] = silu_f(h2[j]);
#pragma unroll
        for (int j = 0; j < 8; ++j) {
            float s = b3[j];
#pragma unroll
            for (int i = 0; i < 32; ++i) s += h2[i] * W3[i * 8 + j];
            Ai[nd * 8 + j] = s;
        }
    } else if (blk < 80) {
        // prep_W: 20 frags of 512 bf16
        int i = (blk - 40) * 256 + tid;   // [0, 10240)
        int j    = i & 7;
        int lane = (i >> 3) & 63;
        int f    = i >> 9;
        int q = lane >> 4, n = lane & 15;
        int L, kf, nt;
        if (f < 4)       { L = 1; kf = 0;             nt = f; }
        else if (f < 12) { L = 2; kf = (f - 4) >> 2;  nt = (f - 4) & 3; }
        else             { L = 3; kf = (f - 12) >> 2; nt = (f - 12) & 3; }
        int k = kf * 32 + q * 8 + j;
        int col = nt * 16 + n;
        float v = 0.0f;
        if (L == 1)      { if (k < 10) v = fcW1[k * 64 + col]; }
        else if (L == 2) v = fcW2[k * 64 + col];
        else             v = fcW3[k * 64 + col];
        Wg[i] = f2bf(v);
    } else if (blk < 592) {
        // prep_B inverse-mapped + histogram/rank
        int linear = (blk - 80) * 256 + tid;   // [0, 131072)
        rank[linear] = atomicAdd(&hist[edst[linear]], 1);
        if (linear < 114688) {                 // 64 * 1792 real elements
            int k = linear / 1792;
            int t = linear - k * 1792;
            int uv, wc;
            if (t < 1024)      { uv = t >> 4;            wc = t & 15; }
            else if (t < 1536) { int r = t - 1024; uv = r >> 3; wc = 16 + (r & 7); }
            else               { int r = t - 1536; uv = r >> 2; wc = 24 + (r & 3); }
            int h  = uv >> 5;
            int q  = (uv >> 3) & 3;
            int j  = uv & 7;
            int nt = wc >> 4;
            int n  = wc & 15;
            int i  = (k << 11) | (h << 10) | (nt << 9) | (((q << 4) | n) << 3) | j;
            Bg[i] = f2bf(fcW4[linear]);
        } else {                               // zero padding: wc in [28,32)
            int z  = linear - 114688;          // [0, 16384)
            int k  = z >> 8;
            int r  = z & 255;
            int uv = r >> 2;
            int c2 = z & 3;
            int h  = uv >> 5;
            int q  = (uv >> 3) & 3;
            int j  = uv & 7;
            int i  = (k << 11) | (h << 10) | (1 << 9) | (((q << 4) | (12 + c2)) << 3) | j;
            Bg[i] = 0;
        }
    } else {
        // zero out
        int t = (blk - 592) * 256 + tid;
        float4 z = float4{0.f, 0.f, 0.f, 0.f};
        for (int r = t; r < 150000; r += 25600)
            ((float4*)outg)[r] = z;
    }
}

// ---------------------------------------------------------------------------
// D2: scan+scatter (512 blocks), atomic-free.  (R7-proven)
// ---------------------------------------------------------------------------
__global__ __launch_bounds__(256)
void scanrank_kernel(const int* __restrict__ edst,
                     const int* __restrict__ hist,
                     const int* __restrict__ rank,
                     int* __restrict__ sortidx)
{
    __shared__ int offs[NN];    // 40000 B
    __shared__ int part[256];
    const int tid = threadIdx.x;

    int loc[40];
    int s = 0;
    if (tid < 250) {
        const int4* h4 = (const int4*)(hist) + tid * 10;
#pragma unroll
        for (int v = 0; v < 10; ++v) {
            int4 x = h4[v];
            loc[v * 4 + 0] = x.x; loc[v * 4 + 1] = x.y;
            loc[v * 4 + 2] = x.z; loc[v * 4 + 3] = x.w;
            s += x.x + x.y + x.z + x.w;
        }
    } else {
#pragma unroll
        for (int r = 0; r < 40; ++r) loc[r] = 0;
    }
    part[tid] = s;
    __syncthreads();
#pragma unroll
    for (int off = 1; off < 256; off <<= 1) {
        int v = (tid >= off) ? part[tid - off] : 0;
        __syncthreads();
        part[tid] += v;
        __syncthreads();
    }
    if (tid < 250) {
        int run = part[tid] - s;
        int base = tid * 40;
#pragma unroll
        for (int r = 0; r < 40; ++r) { offs[base + r] = run; run += loc[r]; }
    }
    __syncthreads();

    int e = blockIdx.x * 256 + tid;
    int d = edst[e];
    sortidx[offs[d] + rank[e]] = e;
}

// ---------------------------------------------------------------------------
// D3: fused edge pipeline, K-SPLIT WAVE PAIRS (R12 structure, race-fixed,
// correctness-proven).  ONE CHANGE vs R12: __launch_bounds__(256, 2).
// R12's (256,4) forced a 128-VGPR cap on a ~160-VGPR-live kernel -> the
// compiler spilled B buffers + accumulators to scratch (WRITE_SIZE 730 MB,
// 1.3 GB HBM/dispatch, 5x slowdown).  With (256,2) the compiler allocates
// freely (~120-140 VGPR, no spill); HW occupancy then comes from ACTUAL
// usage: floor(512/VGPR) = 3-4 waves/SIMD, LDS 39424 allows 4 blocks/CU,
// and the 1024-block grid supplies 16 waves/CU.  Aggregate Bg traffic
// unchanged vs R10 (each wave reads only its k-half).
// LDS: actb 17408 + w3T 17408 + sdb 512 + shb 4096 = 39424.
// ---------------------------------------------------------------------------
__global__ __launch_bounds__(256, 2)
void edge_fused_kernel(const float* __restrict__ pos,
                       const int* __restrict__ batch,
                       const int* __restrict__ esrc,
                       const int* __restrict__ edst,
                       const float* __restrict__ shifts,
                       const float* __restrict__ cell,
                       const unsigned short* __restrict__ Wg,
                       const unsigned short* __restrict__ Bg,
                       const int* __restrict__ sortidx,
                       const float* __restrict__ Ai,
                       const int* __restrict__ hist,
                       float* __restrict__ out_g)
{
    __shared__ __align__(16) unsigned short actb[2][64 * 68]; // 2 x 8704 B
    __shared__ __align__(16) unsigned short w3Tb[2][64 * 68]; // 2 x 8704 B
    __shared__ int   sdb[128];                                // packed s|(d<<16)
    __shared__ __align__(16) float shb[2][64 * 8];            // per-edge sh

    const int tid  = threadIdx.x;
    const int wave = tid >> 6;
    const int lane = tid & 63;
    const int grp  = wave >> 1;      // edge-group within block (0,1)
    const int kh   = wave & 1;       // k-half owned by this wave
    const int q    = lane >> 4;
    const int n    = lane & 15;
    const int i    = blockIdx.x * 128 + grp * 64 + lane;

    unsigned short* actw = actb[grp];
    unsigned short* w3T  = w3Tb[grp];

    // ---- geometry (1 lane = 1 edge; both waves of the pair do identical
    // work and write identical bytes; each wave writes ALL 64 rows itself) --
    int e = sortidx[i];
    int s = esrc[e], d = edst[e];
    sdb[grp * 64 + lane] = s | (d << 16);
    int b = batch[s];
    const float* C = cell + b * 9;
    float sx = shifts[e * 3 + 0], sy = shifts[e * 3 + 1], sz = shifts[e * 3 + 2];
    float vx = pos[d * 3 + 0] - pos[s * 3 + 0] + sx * C[0] + sy * C[3] + sz * C[6];
    float vy = pos[d * 3 + 1] - pos[s * 3 + 1] + sx * C[1] + sy * C[4] + sz * C[7];
    float vz = pos[d * 3 + 2] - pos[s * 3 + 2] + sx * C[2] + sy * C[5] + sz * C[8];
    float len = sqrtf(vx * vx + vy * vy + vz * vz);
    float inv = 1.0f / fmaxf(len, 1e-9f);
    float ux = vx * inv, uy = vy * inv, uz = vz * inv;
    {
        const float s3c  = 1.7320508075688772f;
        const float s5c  = 2.2360679774997896f;
        const float s15c = 3.872983346207417f;
        float* shw = shb[grp];
        *(float4*)&shw[lane * 8]     = float4{s3c * ux, s3c * uy, s3c * uz,
                                              s15c * ux * uz};
        *(float4*)&shw[lane * 8 + 4] = float4{s15c * ux * uy,
                                              s5c * (uy * uy - 0.5f * (ux * ux + uz * uz)),
                                              s15c * uy * uz,
                                              0.5f * s15c * (uz * uz - ux * ux)};
    }

    // soft_one_hot (sqrt(10) cancels with fc_W1's /sqrt(10))
    float embv[10];
    float base = len * 2.75f;
#pragma unroll
    for (int ii = 0; ii < 10; ++ii) {
        float ddv = base - (float)(ii + 1);
        embv[ii] = __expf(-ddv * ddv) * (1.0f / 1.12f);
    }
    {
        unsigned int u0 = pk_bf16(embv[0], embv[1]);
        unsigned int u1 = pk_bf16(embv[2], embv[3]);
        unsigned int u2 = pk_bf16(embv[4], embv[5]);
        unsigned int u3 = pk_bf16(embv[6], embv[7]);
        unsigned int u4 = pk_bf16(embv[8], embv[9]);
        uint2* arow = (uint2*)&actw[lane * 68];
        arow[0] = uint2{u0, u1};
        arow[1] = uint2{u2, u3};
        arow[2] = uint2{u4, 0u};
        arow[3] = uint2{0u, 0u};
        arow[4] = uint2{0u, 0u};
        arow[5] = uint2{0u, 0u};
        arow[6] = uint2{0u, 0u};
        arow[7] = uint2{0u, 0u};
    }

    union AF { unsigned int u[4]; short8 s8; };
    const f32x4 Z4 = (f32x4){0.f, 0.f, 0.f, 0.f};

    auto loadA = [&](int t, int kf) -> AF {
        const unsigned short* ap = &actw[(t * 16 + n) * 68 + kf * 32 + q * 8];
        uint2 a = *(const uint2*)ap;
        uint2 c = *(const uint2*)(ap + 4);
        AF f; f.u[0] = a.x; f.u[1] = a.y; f.u[2] = c.x; f.u[3] = c.y;
        return f;
    };
    auto loadW = [&](int f) -> short8 {   // direct global (L2-resident)
        return *(const short8*)&Wg[(f * 64 + lane) * 8];
    };

    // ---- layer 1: K=32 (padded emb), N=64 (redundant across pair) ----
    {
        AF A1[4];
#pragma unroll
        for (int t = 0; t < 4; ++t) A1[t] = loadA(t, 0);

        // RACE FIX: all waves must finish reading emb before anyone
        // overwrites actw with layer-1 outputs.
        __syncthreads();

#pragma unroll
        for (int nt = 0; nt < 4; ++nt) {
            short8 W0 = loadW(nt);
            f32x4 Cc[4];
#pragma unroll
            for (int t = 0; t < 4; ++t)
                Cc[t] = __builtin_amdgcn_mfma_f32_16x16x32_bf16(A1[t].s8, W0, Z4, 0, 0, 0);
#pragma unroll
            for (int t = 0; t < 4; ++t)
#pragma unroll
                for (int r = 0; r < 4; ++r)
                    actw[(t * 16 + q * 4 + r) * 68 + nt * 16 + n] = f2bf(silu_f(Cc[t][r]));
        }
    }

    // ---- layer 2: K=64 (redundant across pair) ----
    {
        AF A2[4][2];
#pragma unroll
        for (int t = 0; t < 4; ++t)
#pragma unroll
            for (int kf = 0; kf < 2; ++kf) A2[t][kf] = loadA(t, kf);

        // RACE FIX: all waves must finish reading layer-1 activations
        // before anyone overwrites actw with layer-2 outputs.
        __syncthreads();

#pragma unroll
        for (int nt = 0; nt < 4; ++nt) {
            short8 Wk0 = loadW(4 + nt);
            short8 Wk1 = loadW(8 + nt);
            f32x4 Cc[4];
#pragma unroll
            for (int t = 0; t < 4; ++t) {
                Cc[t] = __builtin_amdgcn_mfma_f32_16x16x32_bf16(A2[t][0].s8, Wk0, Z4, 0, 0, 0);
                Cc[t] = __builtin_amdgcn_mfma_f32_16x16x32_bf16(A2[t][1].s8, Wk1, Cc[t], 0, 0, 0);
            }
#pragma unroll
            for (int t = 0; t < 4; ++t)
#pragma unroll
                for (int r = 0; r < 4; ++r)
                    actw[(t * 16 + q * 4 + r) * 68 + nt * 16 + n] = f2bf(silu_f(Cc[t][r] * 0.125f));
        }
    }

    // ---- layer 3: K=64, nt split by k-half -> w3T rows [32*kh, 32*kh+32).
    // Reads actw (own wave wrote all rows), writes SEPARATE buffer w3T with
    // disjoint per-wave rows -> no barrier needed. ----
    {
        AF A3[4][2];
#pragma unroll
        for (int t = 0; t < 4; ++t)
#pragma unroll
            for (int kf = 0; kf < 2; ++kf) A3[t][kf] = loadA(t, kf);
#pragma unroll
        for (int ntl = 0; ntl < 2; ++ntl) {
            int nt = kh * 2 + ntl;
            short8 Wk0 = loadW(12 + nt);
            short8 Wk1 = loadW(16 + nt);
            f32x4 Cc[4];
#pragma unroll
            for (int t = 0; t < 4; ++t) {
                Cc[t] = __builtin_amdgcn_mfma_f32_16x16x32_bf16(A3[t][0].s8, Wk0, Z4, 0, 0, 0);
                Cc[t] = __builtin_amdgcn_mfma_f32_16x16x32_bf16(A3[t][1].s8, Wk1, Cc[t], 0, 0, 0);
            }
#pragma unroll
            for (int t = 0; t < 4; ++t)
#pragma unroll
                for (int r = 0; r < 4; ++r)
                    w3T[(nt * 16 + n) * 68 + t * 16 + q * 4 + r] = f2bf(silu_f(Cc[t][r] * 0.125f));
        }
    }

    // ---- register double-buffered B stream over this wave's 16 chunks ----
    const unsigned char* BgB = (const unsigned char*)Bg;
    short8 BA[8], BB[8];
    const int cbase = kh * 16;   // chunks [cbase, cbase+16) = k [32kh, 32kh+32)

    auto LOADB = [&](short8 (&Bf)[8], int c) {
#pragma unroll
        for (int f = 0; f < 8; ++f)
            Bf[f] = *(const short8*)(BgB +
                (((size_t)((c * 8 + f) * 64 + lane)) << 4));
    };

    LOADB(BA, cbase);   // latency hides under P-pack below

    // k-invariant P fragments: P[e, uv=h*32+q*8+j] = As[h*4+q]*Ad[j]
    AF P[4][2];
#pragma unroll
    for (int t = 0; t < 4; ++t) {
        int eL = grp * 64 + t * 16 + n;
        int sd = sdb[eL];
        int ss  = sd & 0xFFFF;
        int dd2 = sd >> 16;
        float As0 = Ai[ss * 8 + q];
        float As1 = Ai[ss * 8 + 4 + q];
        float4 d0 = *(const float4*)&Ai[dd2 * 8];
        float4 d1 = *(const float4*)&Ai[dd2 * 8 + 4];
        float Ad[8] = {d0.x, d0.y, d0.z, d0.w, d1.x, d1.y, d1.z, d1.w};
#pragma unroll
        for (int h = 0; h < 2; ++h) {
            float s0 = h ? As1 : As0;
            P[t][h].u[0] = pk_bf16(s0 * Ad[0], s0 * Ad[1]);
            P[t][h].u[1] = pk_bf16(s0 * Ad[2], s0 * Ad[3]);
            P[t][h].u[2] = pk_bf16(s0 * Ad[4], s0 * Ad[5]);
            P[t][h].u[3] = pk_bf16(s0 * Ad[6], s0 * Ad[7]);
        }
    }

    f32x4 out[4][2];
#pragma unroll
    for (int t = 0; t < 4; ++t)
#pragma unroll
        for (int nt = 0; nt < 2; ++nt)
            out[t][nt] = (f32x4){0.f, 0.f, 0.f, 0.f};

    // fragment index f = kk*4 + h*2 + nt  (matches Bg layout)
    auto COMPUTE = [&](short8 (&Bf)[8], int c) {
#pragma unroll
        for (int kk = 0; kk < 2; ++kk) {
            int k = c * 2 + kk;
#pragma unroll
            for (int t = 0; t < 4; ++t) {
                uint2 v = *(const uint2*)&w3T[k * 68 + t * 16 + q * 4];
                float w0 = __uint_as_float(v.x << 16);
                float w1 = __uint_as_float(v.x & 0xFFFF0000u);
                float w2 = __uint_as_float(v.y << 16);
                float w3 = __uint_as_float(v.y & 0xFFFF0000u);
#pragma unroll
                for (int nt = 0; nt < 2; ++nt) {
                    f32x4 Q = __builtin_amdgcn_mfma_f32_16x16x32_bf16(
                        P[t][0].s8, Bf[kk * 4 + nt], Z4, 0, 0, 0);
                    Q = __builtin_amdgcn_mfma_f32_16x16x32_bf16(
                        P[t][1].s8, Bf[kk * 4 + 2 + nt], Q, 0, 0, 0);
                    out[t][nt][0] += w0 * Q[0];
                    out[t][nt][1] += w1 * Q[1];
                    out[t][nt][2] += w2 * Q[2];
                    out[t][nt][3] += w3 * Q[3];
                }
            }
        }
    };

#pragma unroll 1
    for (int cp = 0; cp < 8; ++cp) {
        int c0 = cbase + cp * 2, c1 = c0 + 1;
        LOADB(BB, c1);                  // prefetch odd chunk
        COMPUTE(BA, c0);                // hides BB's latency
        if (cp < 7) LOADB(BA, c0 + 2);  // prefetch next even chunk
        COMPUTE(BB, c1);                // hides BA's latency
    }

    // ---- feat overlay: wave kh=0 -> actb[grp], kh=1 -> w3Tb[grp].
    // Barrier: all actw/w3T reads (layer-3 A3 + B-loop w3) are done. ----
    __syncthreads();

    float* featMine = (float*)(kh == 0 ? actw : w3T);   // [64][33] fp32
#pragma unroll
    for (int t = 0; t < 4; ++t) {
#pragma unroll
        for (int r = 0; r < 4; ++r) {
            int row = t * 16 + q * 4 + r;
            featMine[row * 33 + n]      = out[t][0][r];
            featMine[row * 33 + 16 + n] = out[t][1][r];
        }
    }

    // Barrier: both halves' feats visible to the pair.
    __syncthreads();

    // ---- epilogue: wave kh reduces edges [32kh, 32kh+32) over
    // featA+featB using the precomputed sh table ----
    const float* featA = (const float*)actw;
    const float* featB = (const float*)w3T;

    if (lane < 60) {
        int j = lane;
        int cc, sidx = 0;
        bool is0 = (j < 16);
        if (j < 16)      { cc = j; }
        else if (j < 40) { cc = 16 + (j - 16) / 3; sidx = (j - 16) % 3; }
        else             { cc = 24 + (j - 40) / 5; sidx = 3 + (j - 40) % 5; }

        const float* shw = shb[grp];
        const int e0 = kh * 32;
        int cur_d = sdb[grp * 64 + e0] >> 16;
        float acc = 0.f;
        for (int e2 = e0; e2 < e0 + 32; ++e2) {
            int d_e = sdb[grp * 64 + e2] >> 16;   // wave-uniform
            if (d_e != cur_d) {
                int cnt = hist[cur_d];
                atomicAdd(&out_g[cur_d * 60 + j], acc * (1.0f / 64.0f) / (float)cnt);
                acc = 0.f;
                cur_d = d_e;
            }
            float f  = featA[e2 * 33 + cc] + featB[e2 * 33 + cc];
            float sh = shw[e2 * 8 + sidx];
            if (is0) sh = 1.0f;
            acc += f * sh;
        }
        int cnt = hist[cur_d];
        atomicAdd(&out_g[cur_d * 60 + j], acc * (1.0f / 64.0f) / (float)cnt);
    }
}

extern "C" void kernel_launch(void* const* d_in, const int* in_sizes, int n_in,
                              void* d_out, int out_size, void* d_ws, size_t ws_size,
                              hipStream_t stream)
{
    const float* pos     = (const float*)d_in[0];
    const int*   A       = (const int*)d_in[1];
    const int*   batch   = (const int*)d_in[2];
    const int*   esrc    = (const int*)d_in[3];
    const int*   edst    = (const int*)d_in[4];
    const float* shifts  = (const float*)d_in[5];
    const float* cell    = (const float*)d_in[6];
    const float* emb_tab = (const float*)d_in[7];
    const float* fitW1   = (const float*)d_in[8];
    const float* fitb1   = (const float*)d_in[9];
    const float* fitW2   = (const float*)d_in[10];
    const float* fitb2   = (const float*)d_in[11];
    const float* fitW3   = (const float*)d_in[12];
    const float* fitb3   = (const float*)d_in[13];
    const float* fcW1    = (const float*)d_in[14];
    const float* fcW2    = (const float*)d_in[15];
    const float* fcW3    = (const float*)d_in[16];
    const float* fcW4    = (const float*)d_in[17];

    float* out = (float*)d_out;

    // workspace layout (all 16B-aligned)
    char* W = (char*)d_ws;
    float* Ai      = (float*)W;  W += (size_t)NN * 8 * 4;        // 320000
    int* sortidx   = (int*)W;    W += (size_t)NE * 4;            // 524288
    int* rank      = (int*)W;    W += (size_t)NE * 4;            // 524288
    int* hist      = (int*)W;    W += (size_t)NN * 4;            // 40000
    unsigned short* Bg = (unsigned short*)W; W += (size_t)131072 * 2;
    unsigned short* Wg = (unsigned short*)W; W += (size_t)10240 * 2;

    // D0: zero hist only (rank is fully overwritten by prep)
    hipMemsetAsync(hist, 0, (size_t)NN * 4, stream);

    // D1: prep (MLP, W/B fragment packing, histogram + rank, out zeroing)
    prep_kernel<<<692, 256, 0, stream>>>(
        A, edst, emb_tab, fitW1, fitb1, fitW2, fitb2, fitW3, fitb3,
        fcW1, fcW2, fcW3, fcW4, hist, rank, out, Ai, Wg, Bg);

    // D2: per-block redundant scan + atomic-free scatter
    scanrank_kernel<<<NE / 256, 256, 0, stream>>>(edst, hist, rank, sortidx);

    // D3: fused edge pipeline (k-split wave pairs, no spill-forcing bounds)
    edge_fused_kernel<<<NE / 128, 256, 0, stream>>>(
        pos, batch, esrc, edst, shifts, cell, Wg, Bg,
        sortidx, Ai, hist, out);
}

// Round 15
// 186.705 us; speedup vs baseline: 2.3102x; 1.0739x over previous
//
#include <hip/hip_runtime.h>
#include <hip/hip_bf16.h>
#include <math.h>

#define NN 10000
#define NE 131072

typedef __attribute__((ext_vector_type(8))) short short8;
typedef __attribute__((ext_vector_type(4))) float f32x4;

__device__ __forceinline__ float silu_f(float x) {
    return x / (1.0f + __expf(-x));
}

// round-to-nearest-even f32 -> bf16 (finite inputs only)
__device__ __forceinline__ unsigned short f2bf(float f) {
    unsigned int u = __float_as_uint(f);
    u += 0x7FFFu + ((u >> 16) & 1u);
    return (unsigned short)(u >> 16);
}

// packed pair via HW v_cvt_pk_bf16_f32 (x = low half)
__device__ __forceinline__ unsigned int pk_bf16(float lo, float hi) {
    __hip_bfloat162 h = __float22bfloat162_rn(float2{lo, hi});
    return *reinterpret_cast<unsigned int*>(&h);
}

// ---------------------------------------------------------------------------
// D1: prep (692 blocks).  hist already zeroed by D0 memset.  (R7-proven)
// ---------------------------------------------------------------------------
__global__ __launch_bounds__(256)
void prep_kernel(const int* __restrict__ A,
                 const int* __restrict__ edst,
                 const float* __restrict__ emb_tab,
                 const float* __restrict__ W1, const float* __restrict__ b1,
                 const float* __restrict__ W2, const float* __restrict__ b2,
                 const float* __restrict__ W3, const float* __restrict__ b3,
                 const float* __restrict__ fcW1,
                 const float* __restrict__ fcW2,
                 const float* __restrict__ fcW3,
                 const float* __restrict__ fcW4,
                 int* __restrict__ hist,
                 int* __restrict__ rank,
                 float* __restrict__ outg,
                 float* __restrict__ Ai,
                 unsigned short* __restrict__ Wg,
                 unsigned short* __restrict__ Bg)
{
    const int blk = blockIdx.x;
    const int tid = threadIdx.x;

    if (blk < 40) {
        // node MLP -> Ai
        int nd = blk * 256 + tid;
        if (nd >= NN) return;
        int a = A[nd];
        float h[16];
#pragma unroll
        for (int i = 0; i < 16; ++i) h[i] = emb_tab[a * 16 + i];
        float h1[64];
#pragma unroll
        for (int j = 0; j < 64; ++j) h1[j] = b1[j];
#pragma unroll
        for (int i = 0; i < 16; ++i) {
            float hv = h[i];
#pragma unroll
            for (int j = 0; j < 64; ++j) h1[j] += hv * W1[i * 64 + j];
        }
#pragma unroll
        for (int j = 0; j < 64; ++j) h1[j] = silu_f(h1[j]);
        float h2[32];
#pragma unroll
        for (int j = 0; j < 32; ++j) h2[j] = b2[j];
#pragma unroll
        for (int i = 0; i < 64; ++i) {
            float hv = h1[i];
#pragma unroll
            for (int j = 0; j < 32; ++j) h2[j] += hv * W2[i * 32 + j];
        }
#pragma unroll
        for (int j = 0; j < 32; ++j) h2[j] = silu_f(h2[j]);
#pragma unroll
        for (int j = 0; j < 8; ++j) {
            float s = b3[j];
#pragma unroll
            for (int i = 0; i < 32; ++i) s += h2[i] * W3[i * 8 + j];
            Ai[nd * 8 + j] = s;
        }
    } else if (blk < 80) {
        // prep_W: 20 frags of 512 bf16
        int i = (blk - 40) * 256 + tid;   // [0, 10240)
        int j    = i & 7;
        int lane = (i >> 3) & 63;
        int f    = i >> 9;
        int q = lane >> 4, n = lane & 15;
        int L, kf, nt;
        if (f < 4)       { L = 1; kf = 0;             nt = f; }
        else if (f < 12) { L = 2; kf = (f - 4) >> 2;  nt = (f - 4) & 3; }
        else             { L = 3; kf = (f - 12) >> 2; nt = (f - 12) & 3; }
        int k = kf * 32 + q * 8 + j;
        int col = nt * 16 + n;
        float v = 0.0f;
        if (L == 1)      { if (k < 10) v = fcW1[k * 64 + col]; }
        else if (L == 2) v = fcW2[k * 64 + col];
        else             v = fcW3[k * 64 + col];
        Wg[i] = f2bf(v);
    } else if (blk < 592) {
        // prep_B inverse-mapped + histogram/rank
        int linear = (blk - 80) * 256 + tid;   // [0, 131072)
        rank[linear] = atomicAdd(&hist[edst[linear]], 1);
        if (linear < 114688) {                 // 64 * 1792 real elements
            int k = linear / 1792;
            int t = linear - k * 1792;
            int uv, wc;
            if (t < 1024)      { uv = t >> 4;            wc = t & 15; }
            else if (t < 1536) { int r = t - 1024; uv = r >> 3; wc = 16 + (r & 7); }
            else               { int r = t - 1536; uv = r >> 2; wc = 24 + (r & 3); }
            int h  = uv >> 5;
            int q  = (uv >> 3) & 3;
            int j  = uv & 7;
            int nt = wc >> 4;
            int n  = wc & 15;
            int i  = (k << 11) | (h << 10) | (nt << 9) | (((q << 4) | n) << 3) | j;
            Bg[i] = f2bf(fcW4[linear]);
        } else {                               // zero padding: wc in [28,32)
            int z  = linear - 114688;          // [0, 16384)
            int k  = z >> 8;
            int r  = z & 255;
            int uv = r >> 2;
            int c2 = z & 3;
            int h  = uv >> 5;
            int q  = (uv >> 3) & 3;
            int j  = uv & 7;
            int i  = (k << 11) | (h << 10) | (1 << 9) | (((q << 4) | (12 + c2)) << 3) | j;
            Bg[i] = 0;
        }
    } else {
        // zero out
        int t = (blk - 592) * 256 + tid;
        float4 z = float4{0.f, 0.f, 0.f, 0.f};
        for (int r = t; r < 150000; r += 25600)
            ((float4*)outg)[r] = z;
    }
}

// ---------------------------------------------------------------------------
// D2: scan+scatter (512 blocks), atomic-free.  (R7-proven)
// ---------------------------------------------------------------------------
__global__ __launch_bounds__(256)
void scanrank_kernel(const int* __restrict__ edst,
                     const int* __restrict__ hist,
                     const int* __restrict__ rank,
                     int* __restrict__ sortidx)
{
    __shared__ int offs[NN];    // 40000 B
    __shared__ int part[256];
    const int tid = threadIdx.x;

    int loc[40];
    int s = 0;
    if (tid < 250) {
        const int4* h4 = (const int4*)(hist) + tid * 10;
#pragma unroll
        for (int v = 0; v < 10; ++v) {
            int4 x = h4[v];
            loc[v * 4 + 0] = x.x; loc[v * 4 + 1] = x.y;
            loc[v * 4 + 2] = x.z; loc[v * 4 + 3] = x.w;
            s += x.x + x.y + x.z + x.w;
        }
    } else {
#pragma unroll
        for (int r = 0; r < 40; ++r) loc[r] = 0;
    }
    part[tid] = s;
    __syncthreads();
#pragma unroll
    for (int off = 1; off < 256; off <<= 1) {
        int v = (tid >= off) ? part[tid - off] : 0;
        __syncthreads();
        part[tid] += v;
        __syncthreads();
    }
    if (tid < 250) {
        int run = part[tid] - s;
        int base = tid * 40;
#pragma unroll
        for (int r = 0; r < 40; ++r) { offs[base + r] = run; run += loc[r]; }
    }
    __syncthreads();

    int e = blockIdx.x * 256 + tid;
    int d = edst[e];
    sortidx[offs[d] + rank[e]] = e;
}

// ---------------------------------------------------------------------------
// D3: fused edge pipeline (R10 structure, 187.2 us proven best: 64 edges/
// wave, 512 blocks, de-staged W/B direct from L2, ZERO barriers, explicit
// register double-buffer BA/BB for the B stream) + T5 s_setprio around the
// MFMA+accumulate cluster.  Waves here are free-running at 2/SIMD and at
// different phases -- the measured regime where setprio pays (attn +4-7%);
// it prioritizes a compute-phase wave over its SIMD-mate's prefetch issue.
// LDS: actb 34816 + sdb 1024 + shb 8192 = 44032 B.
// ---------------------------------------------------------------------------
__global__ __launch_bounds__(256, 2)
void edge_fused_kernel(const float* __restrict__ pos,
                       const int* __restrict__ batch,
                       const int* __restrict__ esrc,
                       const int* __restrict__ edst,
                       const float* __restrict__ shifts,
                       const float* __restrict__ cell,
                       const unsigned short* __restrict__ Wg,
                       const unsigned short* __restrict__ Bg,
                       const int* __restrict__ sortidx,
                       const float* __restrict__ Ai,
                       const int* __restrict__ hist,
                       float* __restrict__ out_g)
{
    __shared__ __align__(16) unsigned short actb[4][64 * 68]; // 4 x 8.5 KB
    __shared__ int   sdb[256];                                // packed s | (d<<16)
    __shared__ __align__(16) float shb[4][64 * 8];            // per-edge sh table

    const int tid  = threadIdx.x;
    const int wave = tid >> 6;
    const int lane = tid & 63;
    const int q    = lane >> 4;
    const int n    = lane & 15;
    const int i    = blockIdx.x * 256 + wave * 64 + lane;

    unsigned short* actw = actb[wave];

    // ---- geometry (1 lane = 1 edge) ----
    int e = sortidx[i];
    int s = esrc[e], d = edst[e];
    sdb[wave * 64 + lane] = s | (d << 16);
    int b = batch[s];
    const float* C = cell + b * 9;
    float sx = shifts[e * 3 + 0], sy = shifts[e * 3 + 1], sz = shifts[e * 3 + 2];
    float vx = pos[d * 3 + 0] - pos[s * 3 + 0] + sx * C[0] + sy * C[3] + sz * C[6];
    float vy = pos[d * 3 + 1] - pos[s * 3 + 1] + sx * C[1] + sy * C[4] + sz * C[7];
    float vz = pos[d * 3 + 2] - pos[s * 3 + 2] + sx * C[2] + sy * C[5] + sz * C[8];
    float len = sqrtf(vx * vx + vy * vy + vz * vz);
    float inv = 1.0f / fmaxf(len, 1e-9f);
    float ux = vx * inv, uy = vy * inv, uz = vz * inv;
    {
        const float s3c  = 1.7320508075688772f;
        const float s5c  = 2.2360679774997896f;
        const float s15c = 3.872983346207417f;
        float* shw = shb[wave];
        *(float4*)&shw[lane * 8]     = float4{s3c * ux, s3c * uy, s3c * uz,
                                              s15c * ux * uz};
        *(float4*)&shw[lane * 8 + 4] = float4{s15c * ux * uy,
                                              s5c * (uy * uy - 0.5f * (ux * ux + uz * uz)),
                                              s15c * uy * uz,
                                              0.5f * s15c * (uz * uz - ux * ux)};
    }

    // soft_one_hot (sqrt(10) cancels with fc_W1's /sqrt(10))
    float embv[10];
    float base = len * 2.75f;
#pragma unroll
    for (int ii = 0; ii < 10; ++ii) {
        float ddv = base - (float)(ii + 1);
        embv[ii] = __expf(-ddv * ddv) * (1.0f / 1.12f);
    }
    {
        unsigned int u0 = pk_bf16(embv[0], embv[1]);
        unsigned int u1 = pk_bf16(embv[2], embv[3]);
        unsigned int u2 = pk_bf16(embv[4], embv[5]);
        unsigned int u3 = pk_bf16(embv[6], embv[7]);
        unsigned int u4 = pk_bf16(embv[8], embv[9]);
        uint2* arow = (uint2*)&actw[lane * 68];
        arow[0] = uint2{u0, u1};
        arow[1] = uint2{u2, u3};
        arow[2] = uint2{u4, 0u};
        arow[3] = uint2{0u, 0u};
        arow[4] = uint2{0u, 0u};
        arow[5] = uint2{0u, 0u};
        arow[6] = uint2{0u, 0u};
        arow[7] = uint2{0u, 0u};
    }
    // all LDS from here on is per-wave: no barrier needed anywhere.

    union AF { unsigned int u[4]; short8 s8; };
    const f32x4 Z4 = (f32x4){0.f, 0.f, 0.f, 0.f};

    auto loadA = [&](int t, int kf) -> AF {
        const unsigned short* ap = &actw[(t * 16 + n) * 68 + kf * 32 + q * 8];
        uint2 a = *(const uint2*)ap;
        uint2 c = *(const uint2*)(ap + 4);
        AF f; f.u[0] = a.x; f.u[1] = a.y; f.u[2] = c.x; f.u[3] = c.y;
        return f;
    };
    auto loadW = [&](int f) -> short8 {   // direct global (L2-resident)
        return *(const short8*)&Wg[(f * 64 + lane) * 8];
    };

    // ---- layer 1: K=32 (padded emb), N=64 ----
    {
        AF A1[4];
#pragma unroll
        for (int t = 0; t < 4; ++t) A1[t] = loadA(t, 0);
#pragma unroll
        for (int nt = 0; nt < 4; ++nt) {
            short8 W0 = loadW(nt);
            f32x4 Cc[4];
#pragma unroll
            for (int t = 0; t < 4; ++t)
                Cc[t] = __builtin_amdgcn_mfma_f32_16x16x32_bf16(A1[t].s8, W0, Z4, 0, 0, 0);
#pragma unroll
            for (int t = 0; t < 4; ++t)
#pragma unroll
                for (int r = 0; r < 4; ++r)
                    actw[(t * 16 + q * 4 + r) * 68 + nt * 16 + n] = f2bf(silu_f(Cc[t][r]));
        }
    }

    // ---- layer 2: K=64 ----
    {
        AF A2[4][2];
#pragma unroll
        for (int t = 0; t < 4; ++t)
#pragma unroll
            for (int kf = 0; kf < 2; ++kf) A2[t][kf] = loadA(t, kf);
#pragma unroll
        for (int nt = 0; nt < 4; ++nt) {
            short8 Wk0 = loadW(4 + nt);
            short8 Wk1 = loadW(8 + nt);
            f32x4 Cc[4];
#pragma unroll
            for (int t = 0; t < 4; ++t) {
                Cc[t] = __builtin_amdgcn_mfma_f32_16x16x32_bf16(A2[t][0].s8, Wk0, Z4, 0, 0, 0);
                Cc[t] = __builtin_amdgcn_mfma_f32_16x16x32_bf16(A2[t][1].s8, Wk1, Cc[t], 0, 0, 0);
            }
#pragma unroll
            for (int t = 0; t < 4; ++t)
#pragma unroll
                for (int r = 0; r < 4; ++r)
                    actw[(t * 16 + q * 4 + r) * 68 + nt * 16 + n] = f2bf(silu_f(Cc[t][r] * 0.125f));
        }
    }

    // ---- layer 3: K=64, epilogue -> w3 transposed [k][edge] in actw ----
    {
        AF A3[4][2];
#pragma unroll
        for (int t = 0; t < 4; ++t)
#pragma unroll
            for (int kf = 0; kf < 2; ++kf) A3[t][kf] = loadA(t, kf);
#pragma unroll
        for (int nt = 0; nt < 4; ++nt) {
            short8 Wk0 = loadW(12 + nt);
            short8 Wk1 = loadW(16 + nt);
            f32x4 Cc[4];
#pragma unroll
            for (int t = 0; t < 4; ++t) {
                Cc[t] = __builtin_amdgcn_mfma_f32_16x16x32_bf16(A3[t][0].s8, Wk0, Z4, 0, 0, 0);
                Cc[t] = __builtin_amdgcn_mfma_f32_16x16x32_bf16(A3[t][1].s8, Wk1, Cc[t], 0, 0, 0);
            }
#pragma unroll
            for (int t = 0; t < 4; ++t)
#pragma unroll
                for (int r = 0; r < 4; ++r)
                    actw[(nt * 16 + n) * 68 + t * 16 + q * 4 + r] = f2bf(silu_f(Cc[t][r] * 0.125f));
        }
    }

    // ---- register double-buffered B stream ----
    const unsigned char* BgB = (const unsigned char*)Bg;
    short8 BA[8], BB[8];

    auto LOADB = [&](short8 (&Bf)[8], int c) {
#pragma unroll
        for (int f = 0; f < 8; ++f)
            Bf[f] = *(const short8*)(BgB +
                (((size_t)((c * 8 + f) * 64 + lane)) << 4));
    };

    LOADB(BA, 0);   // issue chunk-0 loads; latency hides under P-pack below

    // k-invariant P fragments: P[e, uv=h*32+q*8+j] = As[h*4+q]*Ad[j]
    AF P[4][2];
#pragma unroll
    for (int t = 0; t < 4; ++t) {
        int eL = wave * 64 + t * 16 + n;
        int sd = sdb[eL];
        int ss  = sd & 0xFFFF;
        int dd2 = sd >> 16;
        float As0 = Ai[ss * 8 + q];
        float As1 = Ai[ss * 8 + 4 + q];
        float4 d0 = *(const float4*)&Ai[dd2 * 8];
        float4 d1 = *(const float4*)&Ai[dd2 * 8 + 4];
        float Ad[8] = {d0.x, d0.y, d0.z, d0.w, d1.x, d1.y, d1.z, d1.w};
#pragma unroll
        for (int h = 0; h < 2; ++h) {
            float s0 = h ? As1 : As0;
            P[t][h].u[0] = pk_bf16(s0 * Ad[0], s0 * Ad[1]);
            P[t][h].u[1] = pk_bf16(s0 * Ad[2], s0 * Ad[3]);
            P[t][h].u[2] = pk_bf16(s0 * Ad[4], s0 * Ad[5]);
            P[t][h].u[3] = pk_bf16(s0 * Ad[6], s0 * Ad[7]);
        }
    }

    f32x4 out[4][2];
#pragma unroll
    for (int t = 0; t < 4; ++t)
#pragma unroll
        for (int nt = 0; nt < 2; ++nt)
            out[t][nt] = (f32x4){0.f, 0.f, 0.f, 0.f};

    // fragment index f = kk*4 + h*2 + nt  (matches Bg layout)
    // T5: setprio(1) keeps this wave favored through its MFMA cluster.
    auto COMPUTE = [&](short8 (&Bf)[8], int c) {
        __builtin_amdgcn_s_setprio(1);
#pragma unroll
        for (int kk = 0; kk < 2; ++kk) {
            int k = c * 2 + kk;
#pragma unroll
            for (int t = 0; t < 4; ++t) {
                uint2 v = *(const uint2*)&actw[k * 68 + t * 16 + q * 4];
                float w0 = __uint_as_float(v.x << 16);
                float w1 = __uint_as_float(v.x & 0xFFFF0000u);
                float w2 = __uint_as_float(v.y << 16);
                float w3 = __uint_as_float(v.y & 0xFFFF0000u);
#pragma unroll
                for (int nt = 0; nt < 2; ++nt) {
                    f32x4 Q = __builtin_amdgcn_mfma_f32_16x16x32_bf16(
                        P[t][0].s8, Bf[kk * 4 + nt], Z4, 0, 0, 0);
                    Q = __builtin_amdgcn_mfma_f32_16x16x32_bf16(
                        P[t][1].s8, Bf[kk * 4 + 2 + nt], Q, 0, 0, 0);
                    out[t][nt][0] += w0 * Q[0];
                    out[t][nt][1] += w1 * Q[1];
                    out[t][nt][2] += w2 * Q[2];
                    out[t][nt][3] += w3 * Q[3];
                }
            }
        }
        __builtin_amdgcn_s_setprio(0);
    };

#pragma unroll 1
    for (int cp = 0; cp < 16; ++cp) {
        int c0 = cp * 2, c1 = c0 + 1;
        LOADB(BB, c1);                 // prefetch odd chunk
        COMPUTE(BA, c0);               // ~350cy: hides BB's latency
        if (cp < 15) LOADB(BA, c0 + 2);// prefetch next even chunk
        COMPUTE(BB, c1);               // hides BA's latency
    }

    // ---- epilogue: feat rows -> LDS (stride 33), per-wave segmented
    // reduction using the precomputed sh table ----
    float* featL = (float*)actw;   // [64][33] fp32 = 8448 B
#pragma unroll
    for (int t = 0; t < 4; ++t) {
#pragma unroll
        for (int r = 0; r < 4; ++r) {
            int row = t * 16 + q * 4 + r;
            featL[row * 33 + n]      = out[t][0][r];
            featL[row * 33 + 16 + n] = out[t][1][r];
        }
    }
    // same-wave ds write->read: lockstep + compiler lgkmcnt, no barrier needed

    if (lane < 60) {
        int j = lane;
        int cc, sidx = 0;
        bool is0 = (j < 16);
        if (j < 16)      { cc = j; }
        else if (j < 40) { cc = 16 + (j - 16) / 3; sidx = (j - 16) % 3; }
        else             { cc = 24 + (j - 40) / 5; sidx = 3 + (j - 40) % 5; }

        const float* shw = shb[wave];
        int cur_d = sdb[wave * 64] >> 16;
        float acc = 0.f;
        for (int e2 = 0; e2 < 64; ++e2) {
            int d_e = sdb[wave * 64 + e2] >> 16;   // wave-uniform
            if (d_e != cur_d) {
                int cnt = hist[cur_d];
                atomicAdd(&out_g[cur_d * 60 + j], acc * (1.0f / 64.0f) / (float)cnt);
                acc = 0.f;
                cur_d = d_e;
            }
            float f  = featL[e2 * 33 + cc];
            float sh = shw[e2 * 8 + sidx];
            if (is0) sh = 1.0f;
            acc += f * sh;
        }
        int cnt = hist[cur_d];
        atomicAdd(&out_g[cur_d * 60 + j], acc * (1.0f / 64.0f) / (float)cnt);
    }
}

extern "C" void kernel_launch(void* const* d_in, const int* in_sizes, int n_in,
                              void* d_out, int out_size, void* d_ws, size_t ws_size,
                              hipStream_t stream)
{
    const float* pos     = (const float*)d_in[0];
    const int*   A       = (const int*)d_in[1];
    const int*   batch   = (const int*)d_in[2];
    const int*   esrc    = (const int*)d_in[3];
    const int*   edst    = (const int*)d_in[4];
    const float* shifts  = (const float*)d_in[5];
    const float* cell    = (const float*)d_in[6];
    const float* emb_tab = (const float*)d_in[7];
    const float* fitW1   = (const float*)d_in[8];
    const float* fitb1   = (const float*)d_in[9];
    const float* fitW2   = (const float*)d_in[10];
    const float* fitb2   = (const float*)d_in[11];
    const float* fitW3   = (const float*)d_in[12];
    const float* fitb3   = (const float*)d_in[13];
    const float* fcW1    = (const float*)d_in[14];
    const float* fcW2    = (const float*)d_in[15];
    const float* fcW3    = (const float*)d_in[16];
    const float* fcW4    = (const float*)d_in[17];

    float* out = (float*)d_out;

    // workspace layout (all 16B-aligned)
    char* W = (char*)d_ws;
    float* Ai      = (float*)W;  W += (size_t)NN * 8 * 4;        // 320000
    int* sortidx   = (int*)W;    W += (size_t)NE * 4;            // 524288
    int* rank      = (int*)W;    W += (size_t)NE * 4;            // 524288
    int* hist      = (int*)W;    W += (size_t)NN * 4;            // 40000
    unsigned short* Bg = (unsigned short*)W; W += (size_t)131072 * 2;
    unsigned short* Wg = (unsigned short*)W; W += (size_t)10240 * 2;

    // D0: zero hist only (rank is fully overwritten by prep)
    hipMemsetAsync(hist, 0, (size_t)NN * 4, stream);

    // D1: prep (MLP, W/B fragment packing, histogram + rank, out zeroing)
    prep_kernel<<<692, 256, 0, stream>>>(
        A, edst, emb_tab, fitW1, fitb1, fitW2, fitb2, fitW3, fitb3,
        fcW1, fcW2, fcW3, fcW4, hist, rank, out, Ai, Wg, Bg);

    // D2: per-block redundant scan + atomic-free scatter
    scanrank_kernel<<<NE / 256, 256, 0, stream>>>(edst, hist, rank, sortidx);

    // D3: fused edge pipeline (reg-dbuf B prefetch, barrier-free, + setprio)
    edge_fused_kernel<<<NE / 256, 256, 0, stream>>>(
        pos, batch, esrc, edst, shifts, cell, Wg, Bg,
        sortidx, Ai, hist, out);
}